// Round 7
// baseline (148.136 us; speedup 1.0000x reference)
//
#include <hip/hip_runtime.h>

// C51 distributional projection — zero-atomic scan, barrier-free 1-wave
// pipeline, split LDS in/out buffers.
//
// R6 post-mortem (112 us, 2x worse than R4's 54): (a) stage[52 regs] + d[51
// regs] live across the scan -> allocator spilled an array to scratch
// (WRITE_SIZE 104->209 MB, FETCH 54->108 MB = ~107 MB spill round-trip);
// (b) __syncthreads() after issuing the prefetch compiles to s_waitcnt
// vmcnt(0) -> drained the just-issued loads -> zero overlap (fully serial).
//
// This version:
//   - separate bufIn/bufOut (26 KB/wg, 6 wg/CU): scan reads bufIn[j] INSIDE
//     the loop (no aliasing with its bufOut writes -> the d[51] row buffer is
//     gone -> ~50 fewer live VGPRs -> no spill), writes each output bin once.
//   - NO barriers in the fast path: 1-wave workgroup, all ordering is
//     intra-wave. Compiler inserts precise counted vmcnt waits for the
//     stage-register deps (never vmcnt(0)); per-wave DS ops execute in order,
//     so read-before-write across slab iterations is safe.
//   - pipeline per slab k: ds_write stage->bufIn (waits slab k's loads only)
//     -> issue slab k+1's 13 global_load_dwordx4 -> scan (~2800 cy, loads
//     fly) -> coalesced float4 store of bufOut.
//
// Scan math (unchanged since R3, absmax 3.9e-3): b_j = clip(2.5r + 25 +
// 0.99*beta*(j-25)..., 0, 50) is monotone in j with step 0.99 < 1; after the
// integer-bin adjust upper == lower+1, so targets advance 0/1 per atom and a
// sliding 2-register accumulator emits each of the 51 bins exactly once.

namespace {

constexpr int NA    = 51;
constexpr int BLOCK = 64;            // one wave; lanes == rows per slab
constexpr int ROWS  = 64;
constexpr int NSLAB = 4;             // slabs per workgroup
constexpr int ELEMS = ROWS * NA;     // 3264 floats = 13,056 B per buffer
constexpr int VECS  = ELEMS / 4;     // 816 float4s
constexpr int VPL   = 13;            // float4s per lane (last iter: tid<48)

__device__ __forceinline__ void scan_row(float r, float g, int rb,
                                         const float* __restrict__ in,
                                         float* __restrict__ ob)
{
    int   cur  = 0;
    float accL = 0.0f, accU = 0.0f;

    #pragma unroll
    for (int j = 0; j < NA; ++j) {
        const float d = in[rb + j];                    // ds_read_b32, conflict-free
        const float z = fmaf((float)j, 0.4f, -10.0f);  // support atom z_j
        float t = fmaf(g, z, r);                       // r + 0.99*beta*z_j
        t = fminf(fmaxf(t, -10.0f), 10.0f);
        const float b = (t + 10.0f) * 2.5f;            // in [0, 50]

        const float lf = floorf(b);
        int lower = (int)lf;
        if (b == lf && lower > 0) lower -= 1;          // integer-bin adjust
        // invariant: upper == lower + 1, lower in [0,49]

        const float wl = d * ((float)(lower + 1) - b);
        const float wu = d * (b - (float)lower);

        while (cur < lower) {                          // emit finalized bins
            ob[rb + cur] = accL;
            accL = accU; accU = 0.0f; ++cur;
        }
        accL += wl;
        accU += wu;
    }
    ob[rb + cur]     = accL;
    ob[rb + cur + 1] = accU;                           // cur+1 <= 50
    for (int k = cur + 2; k < NA; ++k) ob[rb + k] = 0.0f;
}

__global__ __launch_bounds__(BLOCK)
void c51_project(const float* __restrict__ next_dist,
                 const float* __restrict__ rewards,
                 const float* __restrict__ bootstrap,
                 float* __restrict__ out,
                 int B)
{
    __shared__ __align__(16) float bufIn[ELEMS];
    __shared__ __align__(16) float bufOut[ELEMS];

    const int tid = threadIdx.x;
    const long long wg_row0 = (long long)blockIdx.x * (ROWS * NSLAB);

    if ((wg_row0 + ROWS * NSLAB) <= (long long)B) {
        // ---- fast path: barrier-free software pipeline over 4 slabs ----
        float r[NSLAB], g[NSLAB];
        #pragma unroll
        for (int k = 0; k < NSLAB; ++k) {
            const long long row = wg_row0 + (long long)k * ROWS + tid;
            r[k] = rewards[row];
            g[k] = bootstrap[row] * 0.99f;
        }

        // prologue: issue slab 0's loads
        float4 stage[VPL];
        {
            const float4* __restrict__ in4 =
                (const float4*)(next_dist + wg_row0 * NA);
            #pragma unroll
            for (int i = 0; i < VPL; ++i) {
                const int v = tid + i * BLOCK;
                if (v < VECS) stage[i] = in4[v];
            }
        }

        #pragma unroll
        for (int k = 0; k < NSLAB; ++k) {
            // stage slab k into bufIn — compiler emits COUNTED vmcnt waits
            // for the stage-register deps (slab k's loads), not vmcnt(0).
            {
                float4* l4 = (float4*)bufIn;
                #pragma unroll
                for (int i = 0; i < VPL; ++i) {
                    const int v = tid + i * BLOCK;
                    if (v < VECS) l4[v] = stage[i];
                }
            }
            // issue slab k+1's loads NOW — in flight across the scan.
            // (WAR on stage[] regs is resolved at ds_write issue; safe.)
            if (k + 1 < NSLAB) {
                const float4* __restrict__ n4 =
                    (const float4*)(next_dist + (wg_row0 + (long long)(k + 1) * ROWS) * NA);
                #pragma unroll
                for (int i = 0; i < VPL; ++i) {
                    const int v = tid + i * BLOCK;
                    if (v < VECS) stage[i] = n4[v];
                }
            }

            // scan: bufIn -> bufOut (no aliasing; per-wave DS ops are
            // in-order, so no barrier needed between iterations)
            scan_row(r[k], g[k], tid * NA, bufIn, bufOut);

            // coalesced store of slab k
            {
                float4* __restrict__ o4 =
                    (float4*)(out + (wg_row0 + (long long)k * ROWS) * NA);
                const float4* __restrict__ s4 = (const float4*)bufOut;
                #pragma unroll
                for (int i = 0; i < VPL; ++i) {
                    const int v = tid + i * BLOCK;
                    if (v < VECS) o4[v] = s4[v];
                }
            }
        }
    } else {
        // ---- tail path (last workgroup only): guarded, unpipelined ----
        for (int k = 0; k < NSLAB; ++k) {
            const long long base_row = wg_row0 + (long long)k * ROWS;
            const int rows_here = (int)min((long long)ROWS, (long long)B - base_row);
            if (rows_here <= 0) break;
            const int elems_here = rows_here * NA;
            const long long base_elem = base_row * NA;

            float r = 0.0f, g = 0.0f;
            if (tid < rows_here) {
                r = rewards[base_row + tid];
                g = bootstrap[base_row + tid] * 0.99f;
            }
            for (int e = tid; e < elems_here; e += BLOCK)
                bufIn[e] = next_dist[base_elem + e];
            __syncthreads();
            if (tid < rows_here) scan_row(r, g, tid * NA, bufIn, bufOut);
            __syncthreads();
            for (int e = tid; e < elems_here; e += BLOCK)
                out[base_elem + e] = bufOut[e];
            __syncthreads();
        }
    }
}

} // namespace

extern "C" void kernel_launch(void* const* d_in, const int* in_sizes, int n_in,
                              void* d_out, int out_size, void* d_ws, size_t ws_size,
                              hipStream_t stream)
{
    const float* next_dist = (const float*)d_in[0];
    const float* rewards   = (const float*)d_in[1];
    const float* bootstrap = (const float*)d_in[2];
    float* out = (float*)d_out;

    const int B = in_sizes[1];                          // rewards element count
    const int rows_per_wg = ROWS * NSLAB;               // 256
    const int nblocks = (B + rows_per_wg - 1) / rows_per_wg;  // 2048 for B=524288

    c51_project<<<dim3(nblocks), dim3(BLOCK), 0, stream>>>(
        next_dist, rewards, bootstrap, out, B);
}